// Round 15
// baseline (371.005 us; speedup 1.0000x reference)
//
#include <hip/hip_runtime.h>

// ---------------------------------------------------------------------------
// meta_model: out = (w0*sig(Ll Ll^T) + w1*sig((La La^T)*aa) + w2*sig((Lm Lm^T)*mod)
//                    - sig(Lu Lu^T)) * adj + sig(Lu Lu^T)
// with L* = mlp(feat), w = softmax(ws)
//
// R14 = REVERT TO BEST (R9, 361 us). 14 structurally independent schedules
// all land at 2.2-3.1 TB/s delivered HBM BW with FETCH at the compulsory
// floor; the mixed 4-read+1-write strided stream shape is BW-ceiling-bound
// at ~3 TB/s on this machine. R9 was the fastest measured variant:
//   - fj frags double-buffered in REGISTERS via asm global_load_dwordx4
//     (asm defs cannot be remat'd/sunk); fj(s+1) loaded during step s
//   - ew TRIPLE-buffered in LDS, filled 2 steps ahead by global_load_lds
//     (row-linear 256B/row source)
//   - two counted waits per step: vmcnt(23) pre-compute, vmcnt(21)
//     pre-barrier; fills never drained mid-flight
//   - ew bank swizzle: source col ^= 4*(row&7) floats, read addr matches
//   - block = 256 thr / 4 waves; wave owns one 16x16 col tile per step;
//     block = 16 rows x 2048-col strip, 32 steps; grid 2048 = 512 x 4.
// ---------------------------------------------------------------------------

typedef __attribute__((ext_vector_type(8))) short short8;
typedef __attribute__((ext_vector_type(4))) float f32x4;

__device__ __forceinline__ unsigned short f2bf(float x) {
  union { float f; unsigned u; } v; v.f = x;
  unsigned u = v.u + 0x7FFFu + ((v.u >> 16) & 1u);   // round-to-nearest-even
  return (unsigned short)(u >> 16);
}

__device__ __forceinline__ float sigf(float x) {
  float e = __builtin_amdgcn_exp2f(-1.4426950408889634f * x);
  return __builtin_amdgcn_rcpf(1.0f + e);
}

__device__ __forceinline__ void gload_lds16(const float* g, float* l) {
  __builtin_amdgcn_global_load_lds(
      (const __attribute__((address_space(1))) void*)g,
      (__attribute__((address_space(3))) void*)l, 16, 0, 0);
}
__device__ __forceinline__ void gload_lds16u(const unsigned short* g, unsigned short* l) {
  __builtin_amdgcn_global_load_lds(
      (const __attribute__((address_space(1))) void*)g,
      (__attribute__((address_space(3))) void*)l, 16, 0, 0);
}

__device__ __forceinline__ unsigned lds_off(const void* p) {
  return (unsigned)(uintptr_t)(const __attribute__((address_space(3))) void*)p;
}
__device__ __forceinline__ f32x4 ds_read_f32x4(unsigned a) {
  f32x4 d;
  asm volatile("ds_read_b128 %0, %1" : "=v"(d) : "v"(a));
  return d;
}
__device__ __forceinline__ short8 ds_read_frag(unsigned a) {
  short8 d;
  asm volatile("ds_read_b128 %0, %1" : "=v"(d) : "v"(a));
  return d;
}

// --------------------------- stage A0: feat -> frag -------------------------
__global__ __launch_bounds__(256) void k_featfrag(const float* __restrict__ feat,
                                                  unsigned short* __restrict__ dst) {
  int t = blockIdx.x * 256 + threadIdx.x;   // 8192 rows * 64 chunks
  int row = t >> 6, kc = t & 63;            // 8 cols per thread
  const float4* s = reinterpret_cast<const float4*>(feat + row * 512 + kc * 8);
  float4 v0 = s[0], v1 = s[1];
  short8 o;
  o[0] = f2bf(v0.x); o[1] = f2bf(v0.y); o[2] = f2bf(v0.z); o[3] = f2bf(v0.w);
  o[4] = f2bf(v1.x); o[5] = f2bf(v1.y); o[6] = f2bf(v1.z); o[7] = f2bf(v1.w);
  int mb = row >> 4, kk = kc >> 2;
  int lane = ((kc & 3) << 4) | (row & 15);
  *reinterpret_cast<short8*>(dst + ((size_t)((mb * 16 + kk) * 64 + lane)) * 8) = o;
}

// --------------------- stage A0w: W1/W2 -> B-frag layout ---------------------
__global__ __launch_bounds__(256) void k_wfrag(
    const float* __restrict__ w1_0, const float* __restrict__ w1_1,
    const float* __restrict__ w1_2, const float* __restrict__ w1_3,
    const float* __restrict__ w2_0, const float* __restrict__ w2_1,
    const float* __restrict__ w2_2, const float* __restrict__ w2_3,
    unsigned short* __restrict__ w1f, unsigned short* __restrict__ w2f) {
  int t = blockIdx.x * 256 + threadIdx.x;
  if (t < 32768) {  // W1frag: [g][kk=16][nb=8][lane=64][j=8]
    int lane = t & 63, nb = (t >> 6) & 7, kk = (t >> 9) & 15, g = t >> 13;
    const float* W = g == 0 ? w1_0 : g == 1 ? w1_1 : g == 2 ? w1_2 : w1_3;
    int q = lane >> 4, r = lane & 15;
    int col = nb * 16 + r;
    short8 o;
#pragma unroll
    for (int j = 0; j < 8; ++j) o[j] = f2bf(W[(kk * 32 + q * 8 + j) * 128 + col]);
    *reinterpret_cast<short8*>(w1f + (size_t)t * 8) = o;
  } else if (t < 40960) {  // W2frag: [g][kk=4][nb=8][lane=64][j=8]
    int t2 = t - 32768;
    int lane = t2 & 63, nb = (t2 >> 6) & 7, kk = (t2 >> 9) & 3, g = t2 >> 11;
    const float* W = g == 0 ? w2_0 : g == 1 ? w2_1 : g == 2 ? w2_2 : w2_3;
    int q = lane >> 4, r = lane & 15;
    int col = nb * 16 + r;
    short8 o;
#pragma unroll
    for (int j = 0; j < 8; ++j) o[j] = f2bf(W[(kk * 32 + q * 8 + j) * 128 + col]);
    *reinterpret_cast<short8*>(w2f + (size_t)t2 * 8) = o;
  }
}

// --------------------- stage A1: H = relu(feat@W1cat + b1) -------------------
__global__ __launch_bounds__(256) void k_gemm1(
    const unsigned short* __restrict__ featf, const unsigned short* __restrict__ w1f,
    const float* __restrict__ b1_0, const float* __restrict__ b1_1,
    const float* __restrict__ b1_2, const float* __restrict__ b1_3,
    unsigned short* __restrict__ hfrag) {
  int bi = blockIdx.x, g = blockIdx.y;
  int lane = threadIdx.x & 63, w = threadIdx.x >> 6;
  int wm = w >> 1, wn = w & 1;
  int q = lane >> 4, r = lane & 15;
  int mbase = 8 * bi + 4 * wm;

  f32x4 s[4][4];
#pragma unroll
  for (int mi = 0; mi < 4; ++mi)
#pragma unroll
    for (int nj = 0; nj < 4; ++nj) s[mi][nj] = (f32x4){0.f, 0.f, 0.f, 0.f};

  for (int kk = 0; kk < 16; ++kk) {
    short8 a[4], b[4];
#pragma unroll
    for (int mi = 0; mi < 4; ++mi)
      a[mi] = *reinterpret_cast<const short8*>(
          featf + ((size_t)(((mbase + mi) * 16 + kk) * 64 + lane)) * 8);
#pragma unroll
    for (int nj = 0; nj < 4; ++nj)
      b[nj] = *reinterpret_cast<const short8*>(
          w1f + ((size_t)(((g * 16 + kk) * 8 + 4 * wn + nj) * 64 + lane)) * 8);
#pragma unroll
    for (int mi = 0; mi < 4; ++mi)
#pragma unroll
      for (int nj = 0; nj < 4; ++nj)
        s[mi][nj] = __builtin_amdgcn_mfma_f32_16x16x32_bf16(a[mi], b[nj], s[mi][nj], 0, 0, 0);
  }

  const float* b1 = g == 0 ? b1_0 : g == 1 ? b1_1 : g == 2 ? b1_2 : b1_3;
#pragma unroll
  for (int nj = 0; nj < 4; ++nj) {
    int cl = 64 * wn + 16 * nj + r;
    float bias = b1[cl];
    int Cg = 128 * g + cl;
    int kkd = Cg >> 5;
    int lane2hi = ((Cg >> 3) & 3) << 4;
    int j2 = Cg & 7;
#pragma unroll
    for (int mi = 0; mi < 4; ++mi) {
#pragma unroll
      for (int v = 0; v < 4; ++v) {
        int R = 128 * bi + 64 * wm + 16 * mi + 4 * q + v;
        float val = fmaxf(s[mi][nj][v] + bias, 0.0f);
        int mb = R >> 4;
        int lane2 = lane2hi | (R & 15);
        hfrag[((size_t)((mb * 16 + kkd) * 64 + lane2)) * 8 + j2] = f2bf(val);
      }
    }
  }
}

// --------------------- stage A2: lat_g = H_g@W2_g + b2 -----------------------
__global__ __launch_bounds__(256) void k_gemm2(
    const unsigned short* __restrict__ hfrag, const unsigned short* __restrict__ w2f,
    const float* __restrict__ b2_0, const float* __restrict__ b2_1,
    const float* __restrict__ b2_2, const float* __restrict__ b2_3,
    unsigned short* __restrict__ latf) {
  int bi = blockIdx.x, g = blockIdx.y;
  int lane = threadIdx.x & 63, w = threadIdx.x >> 6;
  int wm = w >> 1, wn = w & 1;
  int q = lane >> 4, r = lane & 15;
  int mbase = 8 * bi + 4 * wm;

  f32x4 s[4][4];
#pragma unroll
  for (int mi = 0; mi < 4; ++mi)
#pragma unroll
    for (int nj = 0; nj < 4; ++nj) s[mi][nj] = (f32x4){0.f, 0.f, 0.f, 0.f};

#pragma unroll
  for (int kk = 0; kk < 4; ++kk) {
    short8 a[4], b[4];
#pragma unroll
    for (int mi = 0; mi < 4; ++mi)
      a[mi] = *reinterpret_cast<const short8*>(
          hfrag + ((size_t)(((mbase + mi) * 16 + 4 * g + kk) * 64 + lane)) * 8);
#pragma unroll
    for (int nj = 0; nj < 4; ++nj)
      b[nj] = *reinterpret_cast<const short8*>(
          w2f + ((size_t)(((g * 4 + kk) * 8 + 4 * wn + nj) * 64 + lane)) * 8);
#pragma unroll
    for (int mi = 0; mi < 4; ++mi)
#pragma unroll
      for (int nj = 0; nj < 4; ++nj)
        s[mi][nj] = __builtin_amdgcn_mfma_f32_16x16x32_bf16(a[mi], b[nj], s[mi][nj], 0, 0, 0);
  }

  const float* b2 = g == 0 ? b2_0 : g == 1 ? b2_1 : g == 2 ? b2_2 : b2_3;
#pragma unroll
  for (int nj = 0; nj < 4; ++nj) {
    int cl = 64 * wn + 16 * nj + r;
    float bias = b2[cl];
    int kkd = cl >> 5;
    int lane2hi = ((cl >> 3) & 3) << 4;
    int j2 = cl & 7;
#pragma unroll
    for (int mi = 0; mi < 4; ++mi) {
#pragma unroll
      for (int v = 0; v < 4; ++v) {
        int R = 128 * bi + 64 * wm + 16 * mi + 4 * q + v;
        float val = s[mi][nj][v] + bias;
        int mb = R >> 4;
        int lane2 = lane2hi | (R & 15);
        latf[((size_t)(((g * 512 + mb) * 4 + kkd) * 64 + lane2)) * 8 + j2] = f2bf(val);
      }
    }
  }
}

// --------------------------- stage B: fused context --------------------------
// Block: 256 thr / 4 waves. Block tile = 16 rows (bi) x 2048 cols (strip cs),
// 32 steps of 64 cols; wave w owns col tile tj = cs*128 + s*4 + w per step.
// s = mfma(fj, fi): lane(q,r) reg v -> out(16*bi + r, 16*tj + 4q + v).
// fi: 16 frags in LDS (shared; filled once). fj: reg double-buffer via asm.
// ew: LDS triple buffer, 16 rows x 64 cols x 3 mats per step, filled 2 steps
// ahead, source col pre-swizzled by ^4*(row&7) floats for bank-even reads.

#define FJLD(dst, p, OFF) \
  asm volatile("global_load_dwordx4 %0, %1, off offset:" OFF : "=v"(dst) : "v"(p))

#define LOADFJ(F, TJ)                                                         \
  do {                                                                        \
    const unsigned short* _b = latf + (size_t)(TJ) * 2048 + (size_t)lane * 8; \
    FJLD(F[0][0], _b, "0");    FJLD(F[0][1], _b, "1024");                     \
    FJLD(F[0][2], _b, "2048"); FJLD(F[0][3], _b, "3072");                     \
    _b += GS;                                                                 \
    FJLD(F[1][0], _b, "0");    FJLD(F[1][1], _b, "1024");                     \
    FJLD(F[1][2], _b, "2048"); FJLD(F[1][3], _b, "3072");                     \
    _b += GS;                                                                 \
    FJLD(F[2][0], _b, "0");    FJLD(F[2][1], _b, "1024");                     \
    FJLD(F[2][2], _b, "2048"); FJLD(F[2][3], _b, "3072");                     \
    _b += GS;                                                                 \
    FJLD(F[3][0], _b, "0");    FJLD(F[3][1], _b, "1024");                     \
    FJLD(F[3][2], _b, "2048"); FJLD(F[3][3], _b, "3072");                     \
  } while (0)

#define GRAM(FC, G, OUTV)                                                     \
  do {                                                                        \
    short8 _f0 = ds_read_frag(fib + (G * 4 + 0) * 1024u + l16);               \
    short8 _f1 = ds_read_frag(fib + (G * 4 + 1) * 1024u + l16);               \
    short8 _f2 = ds_read_frag(fib + (G * 4 + 2) * 1024u + l16);               \
    short8 _f3 = ds_read_frag(fib + (G * 4 + 3) * 1024u + l16);               \
    asm volatile("s_waitcnt lgkmcnt(0)" ::: "memory");                        \
    __builtin_amdgcn_sched_barrier(0);                                        \
    f32x4 _sg = (f32x4){0.f, 0.f, 0.f, 0.f};                                  \
    _sg = __builtin_amdgcn_mfma_f32_16x16x32_bf16(FC[G][0], _f0, _sg, 0, 0, 0); \
    _sg = __builtin_amdgcn_mfma_f32_16x16x32_bf16(FC[G][1], _f1, _sg, 0, 0, 0); \
    _sg = __builtin_amdgcn_mfma_f32_16x16x32_bf16(FC[G][2], _f2, _sg, 0, 0, 0); \
    _sg = __builtin_amdgcn_mfma_f32_16x16x32_bf16(FC[G][3], _f3, _sg, 0, 0, 0); \
    OUTV = _sg;                                                               \
  } while (0)

#define STEP(S, FC, FN)                                                       \
  do {                                                                        \
    int _sn = ((S) + 1 < 32) ? (S) + 1 : 31;                                  \
    LOADFJ(FN, cs * 128 + _sn * 4 + w);                                       \
    __builtin_amdgcn_sched_barrier(0);                                        \
    {                                                                         \
      int _sf = ((S) + 2 < 32) ? (S) + 2 : 31;                                \
      fill_ew(_sf, ((S) + 2) % 3);                                            \
    }                                                                         \
    __builtin_amdgcn_sched_barrier(0);                                        \
    asm volatile("s_waitcnt vmcnt(23)" ::: "memory");                         \
    __builtin_amdgcn_sched_barrier(0);                                        \
    unsigned _ea = ewb + (unsigned)(((S) % 3) * 3072 + rdidx) * 4u;           \
    f32x4 ewa = ds_read_f32x4(_ea);                                           \
    f32x4 ewm = ds_read_f32x4(_ea + 4096u);                                   \
    f32x4 ewj = ds_read_f32x4(_ea + 8192u);                                   \
    f32x4 sg, o4;                                                             \
    GRAM(FC, 0, sg);                                                          \
    o4[0] = w0 * sigf(sg[0]); o4[1] = w0 * sigf(sg[1]);                       \
    o4[2] = w0 * sigf(sg[2]); o4[3] = w0 * sigf(sg[3]);                       \
    GRAM(FC, 1, sg);                                                          \
    o4[0] += w1 * sigf(sg[0] * ewa[0]); o4[1] += w1 * sigf(sg[1] * ewa[1]);   \
    o4[2] += w1 * sigf(sg[2] * ewa[2]); o4[3] += w1 * sigf(sg[3] * ewa[3]);   \
    GRAM(FC, 2, sg);                                                          \
    o4[0] += w2 * sigf(sg[0] * ewm[0]); o4[1] += w2 * sigf(sg[1] * ewm[1]);   \
    o4[2] += w2 * sigf(sg[2] * ewm[2]); o4[3] += w2 * sigf(sg[3] * ewm[3]);   \
    GRAM(FC, 3, sg);                                                          \
    f32x4 res;                                                                \
    { float u0 = sigf(sg[0]), u1 = sigf(sg[1]), u2 = sigf(sg[2]), u3 = sigf(sg[3]); \
      res[0] = ewj[0] * (o4[0] - u0) + u0; res[1] = ewj[1] * (o4[1] - u1) + u1; \
      res[2] = ewj[2] * (o4[2] - u2) + u2; res[3] = ewj[3] * (o4[3] - u3) + u3; } \
    {                                                                         \
      float* _op = out + (size_t)(bi * 16 + r) * 8192 + (size_t)cs * 2048     \
                   + (S) * 64 + 16 * w + 4 * q;                               \
      asm volatile("global_store_dwordx4 %0, %1, off" ::"v"(_op), "v"(res)    \
                   : "memory");                                               \
    }                                                                         \
    asm volatile("s_waitcnt vmcnt(21)" ::: "memory");                         \
    __builtin_amdgcn_s_barrier();                                             \
  } while (0)

__global__ __launch_bounds__(256, 2) void k_ctx(
    const unsigned short* __restrict__ latf,
    const float* __restrict__ adj, const float* __restrict__ aa,
    const float* __restrict__ mod, const float* __restrict__ wsv,
    float* __restrict__ out) {
  __shared__ unsigned short fi_lds[8192];   // 16 KB: 16 frags (4g x 4kk)
  __shared__ float ew_lds[3][3][1024];      // 36 KB: [tbuf][aa|mod|adj][16x64]

  const int bid = blockIdx.x;               // 2048 = 512 rowgroups x 4 strips
  const int cs = bid & 3;
  const int bi = bid >> 2;                  // 16-row block (0..511)
  const int lane = threadIdx.x & 63, w = threadIdx.x >> 6;
  const int q = lane >> 4, r = lane & 15;

  // softmax(ws)
  float s0w = wsv[0], s1w = wsv[1], s2w = wsv[2];
  float mx = fmaxf(fmaxf(s0w, s1w), s2w);
  float e0 = __builtin_amdgcn_exp2f(1.4426950408889634f * (s0w - mx));
  float e1 = __builtin_amdgcn_exp2f(1.4426950408889634f * (s1w - mx));
  float e2 = __builtin_amdgcn_exp2f(1.4426950408889634f * (s2w - mx));
  float inv = __builtin_amdgcn_rcpf(e0 + e1 + e2);
  float w0 = e0 * inv, w1 = e1 * inv, w2 = e2 * inv;

  const size_t GS = (size_t)512 * 2048;     // latf elements per latent

  // ew fill: wave w fills rows [4w,4w+4) of each matrix; 1 instr = 4 rows x
  // 256 B; source col pre-swizzled so LDS reads are bank-even.
  auto fill_ew = [&](int s2, int buf) {
    int rl = lane >> 4;                     // row within chunk (0..3)
    int fx = lane & 15;                     // 16B unit within row
    int lrow = 4 * w + rl;                  // tile row 0..15
    int scol = 4 * (fx ^ (lrow & 7));       // swizzled float col (0..60)
    size_t ga = (size_t)(bi * 16 + lrow) * 8192 + (size_t)cs * 2048
              + (size_t)s2 * 64 + scol;
    gload_lds16(aa + ga, &ew_lds[buf][0][w * 256]);
    gload_lds16(mod + ga, &ew_lds[buf][1][w * 256]);
    gload_lds16(adj + ga, &ew_lds[buf][2][w * 256]);
  };

  // ---- prologue ----
  // fi: wave w fills gram w's 4 frags (rows 16bi..16bi+15)
#pragma unroll
  for (int kk = 0; kk < 4; ++kk)
    gload_lds16u(latf + GS * w + (size_t)(bi * 4 + kk) * 512 + lane * 8,
                 &fi_lds[(w * 4 + kk) * 512]);
  fill_ew(0, 0);
  fill_ew(1, 1);

  short8 fjA[4][4], fjB[4][4];
  LOADFJ(fjA, cs * 128 + 0 * 4 + w);
  asm volatile("s_waitcnt vmcnt(0)" ::: "memory");
  __builtin_amdgcn_s_barrier();

  const unsigned fib = lds_off(fi_lds);
  const unsigned ewb = lds_off(&ew_lds[0][0][0]);
  const unsigned l16 = (unsigned)lane * 16u;
  // ew read float index: row r, logical col 16w+4q, phys col ^ 4*(r&7)
  const unsigned rdidx = (unsigned)(r * 64 + ((16 * w + 4 * q) ^ (4 * (r & 7))));

  for (int s = 0; s < 32; s += 2) {
    STEP(s, fjA, fjB);
    STEP(s + 1, fjB, fjA);
  }
}

// ------------------------------------------------------------------------------
extern "C" void kernel_launch(void* const* d_in, const int* in_sizes, int n_in,
                              void* d_out, int out_size, void* d_ws, size_t ws_size,
                              hipStream_t stream) {
  const float* feat = (const float*)d_in[0];
  const float* adj  = (const float*)d_in[1];
  const float* aa   = (const float*)d_in[2];
  const float* mod  = (const float*)d_in[3];
  // g order: 0=link, 1=aa, 2=mod, 3=unlink
  const float* W1g[4] = {(const float*)d_in[4], (const float*)d_in[12],
                         (const float*)d_in[16], (const float*)d_in[8]};
  const float* b1g[4] = {(const float*)d_in[5], (const float*)d_in[13],
                         (const float*)d_in[17], (const float*)d_in[9]};
  const float* W2g[4] = {(const float*)d_in[6], (const float*)d_in[14],
                         (const float*)d_in[18], (const float*)d_in[10]};
  const float* b2g[4] = {(const float*)d_in[7], (const float*)d_in[15],
                         (const float*)d_in[19], (const float*)d_in[11]};
  const float* wsv = (const float*)d_in[20];
  float* out = (float*)d_out;

  // workspace layout (elements of ushort)
  unsigned short* featf = (unsigned short*)d_ws;   // 4,194,304 elems (8 MiB)
  unsigned short* hfrag = featf + 4194304;         // 4,194,304
  unsigned short* latf  = hfrag + 4194304;         // 4,194,304
  unsigned short* w1f   = latf + 4194304;          //   262,144
  unsigned short* w2f   = w1f + 262144;            //    65,536
  if (ws_size < 25821184) return;

  k_featfrag<<<2048, 256, 0, stream>>>(feat, featf);
  k_wfrag<<<160, 256, 0, stream>>>(W1g[0], W1g[1], W1g[2], W1g[3],
                                   W2g[0], W2g[1], W2g[2], W2g[3], w1f, w2f);
  k_gemm1<<<dim3(64, 4), 256, 0, stream>>>(featf, w1f, b1g[0], b1g[1], b1g[2], b1g[3], hfrag);
  k_gemm2<<<dim3(64, 4), 256, 0, stream>>>(hfrag, w2f, b2g[0], b2g[1], b2g[2], b2g[3], latf);
  k_ctx<<<2048, 256, 0, stream>>>(latf, adj, aa, mod, wsv, out);
}